// Round 2
// baseline (345.348 us; speedup 1.0000x reference)
//
#include <hip/hip_runtime.h>

// Problem constants (from reference)
#define IN_FEATURES 4096
#define RANK 64
#define NUM_EXPERTS 8
#define KDIM 512          // NUM_EXPERTS * RANK (GEMM K)
#define TOKENS 16384      // B*S = 4*4096      (GEMM M)
#define SCALING 1.0f      // ALPHA / RANK = 64/64

// 256x256 8-phase GEMM (m201-style schedule, plain HIP)
#define BM 256
#define BN 256
#define BK 64
#define NKT (KDIM / BK)   // 8 K-tiles
#define NIT (NKT / 2)     // 4 iterations, 2 K-tiles each

typedef __bf16 bf16x8 __attribute__((ext_vector_type(8)));
typedef float f32x4 __attribute__((ext_vector_type(4)));

__device__ __forceinline__ unsigned short f2bf(float f) {
  union { float f; unsigned int u; } v; v.f = f;
  unsigned int u = v.u;
  u += 0x7fffu + ((u >> 16) & 1u);   // round-to-nearest-even
  return (unsigned short)(u >> 16);
}

__device__ __forceinline__ void gload_lds16(const unsigned short* g, unsigned short* l) {
  __builtin_amdgcn_global_load_lds(
      (const __attribute__((address_space(1))) void*)g,
      (__attribute__((address_space(3))) void*)l,
      16, 0, 0);
}

// Merged pack kernel. Each thread emits 4 bf16 (ushort4, 8B store).
//   gid <  QN4 : q[t, k*64+r0..3]  = bf16(w[t,k] * p[t,r])
//   gid >= QN4 : Bt[d, k*64+r0..3] = bf16(A[k,d,r] * mask[k,d,r] * SCALING)
#define QN4 ((long)TOKENS * KDIM / 4)        // 2,097,152
#define BN4 ((long)IN_FEATURES * KDIM / 4)   //   524,288
__global__ void __launch_bounds__(256) pack_both(
    const float* __restrict__ p, const float* __restrict__ w,
    const float* __restrict__ A, const float* __restrict__ mask,
    unsigned short* __restrict__ q, unsigned short* __restrict__ Bt) {
  long gid = (long)blockIdx.x * 256 + threadIdx.x;
  if (gid < QN4) {
    int idx = (int)gid;            // t*128 + k*16 + r4
    int t = idx >> 7;
    int k = (idx >> 4) & 7;
    int r0 = (idx & 15) * 4;
    float wk = w[t * NUM_EXPERTS + k];
    float4 pv = *(const float4*)&p[t * RANK + r0];
    ushort4 o;
    o.x = f2bf(wk * pv.x);
    o.y = f2bf(wk * pv.y);
    o.z = f2bf(wk * pv.z);
    o.w = f2bf(wk * pv.w);
    *(ushort4*)&q[(long)t * KDIM + k * RANK + r0] = o;
  } else {
    int idx = (int)(gid - QN4);    // d*128 + k*16 + r4
    int d = idx >> 7;
    int k = (idx >> 4) & 7;
    int r0 = (idx & 15) * 4;
    long src = ((long)k * IN_FEATURES + d) * RANK + r0;
    float4 a = *(const float4*)&A[src];
    float4 m = *(const float4*)&mask[src];
    ushort4 o;
    o.x = f2bf(a.x * m.x * SCALING);
    o.y = f2bf(a.y * m.y * SCALING);
    o.z = f2bf(a.z * m.z * SCALING);
    o.w = f2bf(a.w * m.w * SCALING);
    *(ushort4*)&Bt[(long)d * KDIM + k * RANK + r0] = o;
  }
}

// C[M,N] = q[M,K] @ Bt[N,K]^T. 256x256 tile, BK=64, 8 waves (2M x 4N),
// per-wave 128x64 output = acc[8][4] f32x4. 8-phase schedule, 2 K-tiles/iter.
// Counted vmcnt(4) only at phases 4/8. LDS chunk swizzle both-sides (rule 21).
// GRID IS M-MAJOR: blockIdx.x = M-tile (64), blockIdx.y = N-tile (16).
// Rationale: linear id = x + 64*y, hardware XCD = id % 8 = x % 8, so all 16
// N-blocks sharing a q-panel carry the same x -> same XCD -> q-panel is
// L2-missed once instead of 8x (L2-miss traffic ~130 MiB -> ~48 MiB).
__global__ void __launch_bounds__(512, 2) gemm_kernel(
    const unsigned short* __restrict__ q,   // [TOKENS, KDIM]
    const unsigned short* __restrict__ Bt,  // [IN_FEATURES, KDIM]
    float* __restrict__ out) {              // [TOKENS, IN_FEATURES]
  __shared__ __align__(16) unsigned short sA[2][2][128 * BK];  // 64 KiB
  __shared__ __align__(16) unsigned short sB[2][2][128 * BK];  // 64 KiB

  const int tid = threadIdx.x;
  const int lane = tid & 63;
  const int wid = tid >> 6;
  const int u = lane & 15;        // fragment row-within-16
  const int quad = lane >> 4;     // k-quad / output row group
  const int hA = wid >> 2;        // which A staging half this wave reads
  const int hB = (wid & 3) >> 1;  // which B staging half
  const int rB = (wid & 1) * 64;  // row base within B half
  const int wn = (wid & 3) * 64;  // col base within block tile

  const int m0 = blockIdx.x * BM;   // M-major grid (see comment above)
  const int n0 = blockIdx.y * BN;

  f32x4 acc[8][4];
#pragma unroll
  for (int i = 0; i < 8; ++i)
#pragma unroll
    for (int j = 0; j < 4; ++j)
      acc[i][j] = (f32x4){0.f, 0.f, 0.f, 0.f};

  // Staging: each thread stages chunks c0=tid, c1=tid+512 of a 128x64
  // half-tile (1024 x 16B chunks). LDS dest linear; global src swizzled.
  const int c0 = tid, c1 = tid + 512;
  const int row0 = c0 >> 3, row1 = c1 >> 3;
  const int log0 = (c0 & 7) ^ (row0 & 7), log1 = (c1 & 7) ^ (row1 & 7);
  const unsigned short* gA0 = q + (m0 + row0) * KDIM + log0 * 8;
  const unsigned short* gA1 = q + (m0 + row1) * KDIM + log1 * 8;
  const unsigned short* gB0 = Bt + (n0 + row0) * KDIM + log0 * 8;
  const unsigned short* gB1 = Bt + (n0 + row1) * KDIM + log1 * 8;
  const int l0 = c0 * 8, l1 = c1 * 8;

  auto stageA = [&](int buf, int h, int kt) {
    int ko = (kt & (NKT - 1)) * BK + h * 128 * KDIM;
    gload_lds16(gA0 + ko, &sA[buf][h][l0]);
    gload_lds16(gA1 + ko, &sA[buf][h][l1]);
  };
  auto stageB = [&](int buf, int h, int kt) {
    int ko = (kt & (NKT - 1)) * BK + h * 128 * KDIM;
    gload_lds16(gB0 + ko, &sB[buf][h][l0]);
    gload_lds16(gB1 + ko, &sB[buf][h][l1]);
  };

  auto ldA = [&](int buf, int mq, bf16x8 (&a)[2][4]) {
    const unsigned short* base = sA[buf][hA];
#pragma unroll
    for (int ki = 0; ki < 2; ++ki)
#pragma unroll
      for (int f = 0; f < 4; ++f) {
        int r = mq * 64 + f * 16 + u;
        int phys = (ki * 4 + quad) ^ (r & 7);
        a[ki][f] = *(const bf16x8*)&base[r * BK + phys * 8];
      }
  };
  auto ldB = [&](int buf, int nq, bf16x8 (&b)[2][2]) {
    const unsigned short* base = sB[buf][hB];
#pragma unroll
    for (int ki = 0; ki < 2; ++ki)
#pragma unroll
      for (int g = 0; g < 2; ++g) {
        int r = rB + nq * 32 + g * 16 + u;
        int phys = (ki * 4 + quad) ^ (r & 7);
        b[ki][g] = *(const bf16x8*)&base[r * BK + phys * 8];
      }
  };
  auto mfmaQ = [&](int mq, int nq, bf16x8 (&a)[2][4], bf16x8 (&b)[2][2]) {
    __builtin_amdgcn_s_setprio(1);
#pragma unroll
    for (int ki = 0; ki < 2; ++ki)
#pragma unroll
      for (int f = 0; f < 4; ++f)
#pragma unroll
        for (int g = 0; g < 2; ++g)
          acc[mq * 4 + f][nq * 2 + g] = __builtin_amdgcn_mfma_f32_16x16x32_bf16(
              a[ki][f], b[ki][g], acc[mq * 4 + f][nq * 2 + g], 0, 0, 0);
    __builtin_amdgcn_s_setprio(0);
  };
  auto phase_bar = [&]() {
    __builtin_amdgcn_sched_barrier(0);
    __builtin_amdgcn_s_barrier();
  };

  bf16x8 Ar[2][4], B0r[2][2], B1r[2][2];

  // Prologue: steady-state issue order B0,B1,A0,A1(kt0), B0,B1(kt1).
  stageB(0, 0, 0); stageB(0, 1, 0);
  stageA(0, 0, 0); stageA(0, 1, 0);
  stageB(1, 0, 1); stageB(1, 1, 1);
  asm volatile("s_waitcnt vmcnt(4)" ::: "memory");  // kt0 resident; B(kt1) in flight
  phase_bar();

  for (int i = 0; i < NIT; ++i) {
    const int k1 = 2 * i + 1, k2 = 2 * i + 2, k3 = 2 * i + 3;
    // ph1: kt=2i quadrant (mq0,nq0); stage A0(kt+1)->buf1
    ldA(0, 0, Ar); ldB(0, 0, B0r);
    stageA(1, 0, k1);
    phase_bar();
    mfmaQ(0, 0, Ar, B0r);
    phase_bar();
    // ph2: (mq0,nq1); stage A1(kt+1)->buf1
    ldB(0, 1, B1r);
    stageA(1, 1, k1);
    phase_bar();
    mfmaQ(0, 1, Ar, B1r);
    phase_bar();
    // ph3: (mq1,nq1); stage B0(kt+2)->buf0
    ldA(0, 1, Ar);
    stageB(0, 0, k2);
    phase_bar();
    mfmaQ(1, 1, Ar, B1r);
    phase_bar();
    // ph4: (mq1,nq0) from regs; stage B1(kt+2)->buf0; counted wait for kt+1
    stageB(0, 1, k2);
    phase_bar();
    mfmaQ(1, 0, Ar, B0r);
    asm volatile("s_waitcnt vmcnt(4)" ::: "memory");
    phase_bar();
    // ph5: kt=2i+1 (mq0,nq0); stage A0(kt+2)->buf0
    ldA(1, 0, Ar); ldB(1, 0, B0r);
    stageA(0, 0, k2);
    phase_bar();
    mfmaQ(0, 0, Ar, B0r);
    phase_bar();
    // ph6: (mq0,nq1); stage A1(kt+2)->buf0
    ldB(1, 1, B1r);
    stageA(0, 1, k2);
    phase_bar();
    mfmaQ(0, 1, Ar, B1r);
    phase_bar();
    // ph7: (mq1,nq1); stage B0(kt+3)->buf1
    ldA(1, 1, Ar);
    stageB(1, 0, k3);
    phase_bar();
    mfmaQ(1, 1, Ar, B1r);
    phase_bar();
    // ph8: (mq1,nq0) from regs; stage B1(kt+3)->buf1; counted wait for kt+2
    stageB(1, 1, k3);
    phase_bar();
    mfmaQ(1, 0, Ar, B0r);
    asm volatile("s_waitcnt vmcnt(4)" ::: "memory");
    phase_bar();
  }

  // Epilogue: C/D layout col = lane&15, row = quad*4 + reg
#pragma unroll
  for (int mf = 0; mf < 8; ++mf) {
    int row = m0 + hA * 128 + mf * 16 + quad * 4;
#pragma unroll
    for (int rr = 0; rr < 4; ++rr) {
      float* orow = out + (long)(row + rr) * IN_FEATURES + n0 + wn + u;
#pragma unroll
      for (int nf = 0; nf < 4; ++nf)
        orow[nf * 16] = acc[mf][nf][rr];
    }
  }
}

extern "C" void kernel_launch(void* const* d_in, const int* in_sizes, int n_in,
                              void* d_out, int out_size, void* d_ws, size_t ws_size,
                              hipStream_t stream) {
  const float* p    = (const float*)d_in[0];  // [4,4096,64]
  const float* w    = (const float*)d_in[1];  // [4,4096,8]
  const float* A    = (const float*)d_in[2];  // [8,4096,64]
  const float* mask = (const float*)d_in[3];  // [8,4096,64]
  float* out = (float*)d_out;                 // [4,4096,4096]

  unsigned short* q  = (unsigned short*)d_ws;            // 16 MiB bf16 [TOKENS, KDIM]
  unsigned short* Bt = q + (size_t)TOKENS * KDIM;        //  4 MiB bf16 [IN_FEATURES, KDIM]

  int pack_blocks = (int)((QN4 + BN4) / 256);            // 10240
  pack_both<<<pack_blocks, 256, 0, stream>>>(p, w, A, mask, q, Bt);

  dim3 grid(TOKENS / BM, IN_FEATURES / BN);              // (64, 16) M-major
  gemm_kernel<<<grid, dim3(512), 0, stream>>>(q, Bt, out);
}

// Round 3
// 342.629 us; speedup vs baseline: 1.0079x; 1.0079x over previous
//
#include <hip/hip_runtime.h>

// Problem constants (from reference)
#define IN_FEATURES 4096
#define RANK 64
#define NUM_EXPERTS 8
#define KDIM 512          // NUM_EXPERTS * RANK (GEMM K)
#define TOKENS 16384      // B*S = 4*4096      (GEMM M)
#define SCALING 1.0f      // ALPHA / RANK = 64/64

// 256x128 tile, BK=32, 2 blocks/CU co-residency design:
// LDS 48 KiB (<=80), VGPR target <=128 via __launch_bounds__(512,4)
#define BM 256
#define BN 128
#define BK 32
#define NKT (KDIM / BK)   // 16 K-tiles

typedef __bf16 bf16x8 __attribute__((ext_vector_type(8)));
typedef float f32x4 __attribute__((ext_vector_type(4)));

__device__ __forceinline__ unsigned short f2bf(float f) {
  union { float f; unsigned int u; } v; v.f = f;
  unsigned int u = v.u;
  u += 0x7fffu + ((u >> 16) & 1u);   // round-to-nearest-even
  return (unsigned short)(u >> 16);
}

__device__ __forceinline__ void gload_lds16(const unsigned short* g, unsigned short* l) {
  __builtin_amdgcn_global_load_lds(
      (const __attribute__((address_space(1))) void*)g,
      (__attribute__((address_space(3))) void*)l,
      16, 0, 0);
}

// Merged pack kernel. Each thread emits 4 bf16 (ushort4, 8B store).
#define QN4 ((long)TOKENS * KDIM / 4)        // 2,097,152
#define BN4 ((long)IN_FEATURES * KDIM / 4)   //   524,288
__global__ void __launch_bounds__(256) pack_both(
    const float* __restrict__ p, const float* __restrict__ w,
    const float* __restrict__ A, const float* __restrict__ mask,
    unsigned short* __restrict__ q, unsigned short* __restrict__ Bt) {
  long gid = (long)blockIdx.x * 256 + threadIdx.x;
  if (gid < QN4) {
    int idx = (int)gid;            // t*128 + k*16 + r4
    int t = idx >> 7;
    int k = (idx >> 4) & 7;
    int r0 = (idx & 15) * 4;
    float wk = w[t * NUM_EXPERTS + k];
    float4 pv = *(const float4*)&p[t * RANK + r0];
    ushort4 o;
    o.x = f2bf(wk * pv.x);
    o.y = f2bf(wk * pv.y);
    o.z = f2bf(wk * pv.z);
    o.w = f2bf(wk * pv.w);
    *(ushort4*)&q[(long)t * KDIM + k * RANK + r0] = o;
  } else {
    int idx = (int)(gid - QN4);    // d*128 + k*16 + r4
    int d = idx >> 7;
    int k = (idx >> 4) & 7;
    int r0 = (idx & 15) * 4;
    long src = ((long)k * IN_FEATURES + d) * RANK + r0;
    float4 a = *(const float4*)&A[src];
    float4 m = *(const float4*)&mask[src];
    ushort4 o;
    o.x = f2bf(a.x * m.x * SCALING);
    o.y = f2bf(a.y * m.y * SCALING);
    o.z = f2bf(a.z * m.z * SCALING);
    o.w = f2bf(a.w * m.w * SCALING);
    *(ushort4*)&Bt[(long)d * KDIM + k * RANK + r0] = o;
  }
}

// C[M,N] = q[M,K] @ Bt[N,K]^T. 256x128 tile, BK=32, 8 waves (2M x 4N),
// per-wave 128x32 output = acc[8][2] f32x4 (64 VGPR). One __syncthreads per
// K-step: [stage(kt+1)->buf^1; ds-read(kt) from buf; MFMA; sync]. The sync's
// implicit vmcnt(0) makes stage(kt+1) resident; its LDS writes target the
// other buffer so no barrier is needed between stage-issue and reads.
// 2 blocks/CU co-resident (48 KiB LDS, <=128 VGPR): block-level overlap hides
// epilogue stores, prologue latency, and barrier idle (m114 co-scheduling).
// LDS chunk swizzle (BK=32: 4 chunks/row): logical kc at phys = kc^((row>>1)&3),
// applied on BOTH sides (pre-swizzled global source; swizzled ds_read addr).
// Read-side banks: per 16-lane quad group phys = q^((u>>1)&3), u 0..15 ->
// 8 bank-groups x 2 lanes = minimal aliasing.
// GRID M-MAJOR: blockIdx.x = M-tile (64), blockIdx.y = N-tile (32) so all
// N-blocks sharing a q-panel land on the same XCD (id%8 = x%8).
__global__ void __launch_bounds__(512, 4) gemm_kernel(
    const unsigned short* __restrict__ q,   // [TOKENS, KDIM]
    const unsigned short* __restrict__ Bt,  // [IN_FEATURES, KDIM]
    float* __restrict__ out) {              // [TOKENS, IN_FEATURES]
  __shared__ __align__(16) unsigned short sA[2][BM * BK];  // 32 KiB
  __shared__ __align__(16) unsigned short sB[2][BN * BK];  // 16 KiB

  const int tid = threadIdx.x;
  const int lane = tid & 63;
  const int wid = tid >> 6;
  const int u = lane & 15;        // fragment row-within-16 / C col
  const int quad = lane >> 4;     // k-chunk select / C row group
  const int wave_m = (wid >> 2) * 128;
  const int wave_n = (wid & 3) * 32;

  const int m0 = blockIdx.x * BM;   // M-major grid
  const int n0 = blockIdx.y * BN;

  f32x4 acc[8][2];
#pragma unroll
  for (int i = 0; i < 8; ++i)
#pragma unroll
    for (int j = 0; j < 2; ++j)
      acc[i][j] = (f32x4){0.f, 0.f, 0.f, 0.f};

  // Staging: A-tile 256x32 = 1024 chunks (2/thread), B-tile 128x32 = 512 (1/thread).
  // chunk c: row = c>>2, logical kc = (c&3) ^ ((row>>1)&3); LDS dest linear c*16B.
  const int cA0 = tid, cA1 = tid + 512, cB = tid;
  const int rA0 = cA0 >> 2, rA1 = cA1 >> 2, rBr = cB >> 2;
  const int lgA0 = (cA0 & 3) ^ ((rA0 >> 1) & 3);
  const int lgA1 = (cA1 & 3) ^ ((rA1 >> 1) & 3);
  const int lgB  = (cB  & 3) ^ ((rBr >> 1) & 3);
  const unsigned short* gA0 = q  + (m0 + rA0) * KDIM + lgA0 * 8;
  const unsigned short* gA1 = q  + (m0 + rA1) * KDIM + lgA1 * 8;
  const unsigned short* gB  = Bt + (n0 + rBr) * KDIM + lgB  * 8;
  const int lA0 = cA0 * 8, lA1 = cA1 * 8, lB = cB * 8;

  auto stage = [&](int buf, int kt) {
    int ko = (kt & (NKT - 1)) * BK;
    gload_lds16(gA0 + ko, &sA[buf][lA0]);
    gload_lds16(gA1 + ko, &sA[buf][lA1]);
    gload_lds16(gB + ko, &sB[buf][lB]);
  };

  // Prologue
  stage(0, 0);
  __syncthreads();   // vmcnt(0) + barrier: kt0 resident

  const int physv = quad ^ ((u >> 1) & 3);   // swizzled k-chunk slot for reads

  for (int kt = 0; kt < NKT; ++kt) {
    const int buf = kt & 1;
    stage(buf ^ 1, kt + 1);   // last iter stages wrapped kt0 into dead buffer

    const unsigned short* bA = sA[buf];
    const unsigned short* bB = sB[buf];

    bf16x8 bfr[2];
#pragma unroll
    for (int g = 0; g < 2; ++g) {
      int r = wave_n + g * 16 + u;
      bfr[g] = *(const bf16x8*)&bB[r * BK + physv * 8];
    }
    // A fragments in two halves of 4 to bound register pressure
#pragma unroll
    for (int h = 0; h < 2; ++h) {
      bf16x8 af[4];
#pragma unroll
      for (int f = 0; f < 4; ++f) {
        int r = wave_m + (h * 4 + f) * 16 + u;
        af[f] = *(const bf16x8*)&bA[r * BK + physv * 8];
      }
#pragma unroll
      for (int f = 0; f < 4; ++f)
#pragma unroll
        for (int g = 0; g < 2; ++g)
          acc[h * 4 + f][g] = __builtin_amdgcn_mfma_f32_16x16x32_bf16(
              af[f], bfr[g], acc[h * 4 + f][g], 0, 0, 0);
    }
    __syncthreads();   // drains lgkm (reads done) + vmcnt (next tile resident)
  }

  // Epilogue: C/D layout col = lane&15, row = quad*4 + reg
#pragma unroll
  for (int f = 0; f < 8; ++f) {
    int row = m0 + wave_m + f * 16 + quad * 4;
#pragma unroll
    for (int rr = 0; rr < 4; ++rr) {
      float* orow = out + (long)(row + rr) * IN_FEATURES + n0 + wave_n + u;
#pragma unroll
      for (int g = 0; g < 2; ++g)
        orow[g * 16] = acc[f][g][rr];
    }
  }
}

extern "C" void kernel_launch(void* const* d_in, const int* in_sizes, int n_in,
                              void* d_out, int out_size, void* d_ws, size_t ws_size,
                              hipStream_t stream) {
  const float* p    = (const float*)d_in[0];  // [4,4096,64]
  const float* w    = (const float*)d_in[1];  // [4,4096,8]
  const float* A    = (const float*)d_in[2];  // [8,4096,64]
  const float* mask = (const float*)d_in[3];  // [8,4096,64]
  float* out = (float*)d_out;                 // [4,4096,4096]

  unsigned short* q  = (unsigned short*)d_ws;            // 16 MiB bf16 [TOKENS, KDIM]
  unsigned short* Bt = q + (size_t)TOKENS * KDIM;        //  4 MiB bf16 [IN_FEATURES, KDIM]

  int pack_blocks = (int)((QN4 + BN4) / 256);            // 10240
  pack_both<<<pack_blocks, 256, 0, stream>>>(p, w, A, mask, q, Bt);

  dim3 grid(TOKENS / BM, IN_FEATURES / BN);              // (64, 32) M-major
  gemm_kernel<<<grid, dim3(512), 0, stream>>>(q, Bt, out);
}